// Round 6
// baseline (175.482 us; speedup 1.0000x reference)
//
#include <hip/hip_runtime.h>

#define NN 50000
#define EE 800000
#define TE (EE + NN)     // total edges including self loops
#define NB 196           // dst buckets of 256 nodes
#define CHUNK 2048       // edges per bucketize block
#define NBLK ((EE + CHUNK - 1) / CHUNK)   // 391
#define CAP 6144         // max edges per bucket (mean 4096, sd 64 -> +32 sigma)

typedef unsigned int uint;
typedef unsigned short ushort;

__device__ __forceinline__ float lrelu(float v){ return v > 0.f ? v : 0.2f*v; }
// round-to-nearest-even fp32 -> bf16 (top 16 bits), packed pair (lo=a, hi=b)
__device__ __forceinline__ uint pack_bf16(float a, float b){
  uint ua = __float_as_uint(a), ub = __float_as_uint(b);
  ua = (ua + 0x7FFFu + ((ua >> 16) & 1u)) >> 16;
  ub = (ub + 0x7FFFu + ((ub >> 16) & 1u)) & 0xFFFF0000u;
  return ua | ub;
}
__device__ __forceinline__ float bf_lo(uint u){ return __uint_as_float(u << 16); }
__device__ __forceinline__ float bf_hi(uint u){ return __uint_as_float(u & 0xFFFF0000u); }

// ---------------- CSR build (bucketed, no per-edge global atomics) ----------------
__global__ __launch_bounds__(256) void k_zero(int* __restrict__ bcnt){
  int t = threadIdx.x;
  if (t < NB) bcnt[t] = 0;
}

__global__ __launch_bounds__(256) void k_bcount(const int* __restrict__ ei, int* __restrict__ bcnt){
  __shared__ int h[NB];
  int t = threadIdx.x;
  if (t < NB) h[t] = 0;
  __syncthreads();
  int base = blockIdx.x * CHUNK;
  int end = base + CHUNK; if (end > EE) end = EE;
  for (int i = base + t; i < end; i += 256)
    atomicAdd(&h[ei[EE + i] >> 8], 1);
  __syncthreads();
  if (t < NB && h[t]) atomicAdd(&bcnt[t], h[t]);
}

__global__ __launch_bounds__(256) void k_bscan2(const int* __restrict__ bcnt,
                                                int* __restrict__ ebase, int* __restrict__ ecur){
  __shared__ int s[256];
  int t = threadIdx.x;
  int v = (t < NB) ? bcnt[t] : 0;
  s[t] = v;
  __syncthreads();
  for (int off = 1; off < 256; off <<= 1){
    int add = (t >= off) ? s[t-off] : 0;
    __syncthreads();
    s[t] += add;
    __syncthreads();
  }
  if (t < NB){ int ex = s[t] - v; ebase[t] = ex; ecur[t] = ex; }
}

__global__ __launch_bounds__(256) void k_bucketize(const int* __restrict__ ei,
                                                   int* __restrict__ ecur, uint* __restrict__ ebuf){
  __shared__ int h[NB];
  __shared__ int sc[256];
  __shared__ int gdelta[NB];
  __shared__ uint P[CHUNK];
  __shared__ int  A[CHUNK];
  int t = threadIdx.x;
  if (t < NB) h[t] = 0;
  __syncthreads();
  int base = blockIdx.x * CHUNK;
  int end = base + CHUNK; if (end > EE) end = EE;
  int bc = end - base;
  int be[8]; int re[8]; uint pe[8];
  #pragma unroll
  for (int q = 0; q < 8; ++q){
    int i = base + t + q*256;
    be[q] = -1;
    if (i < end){
      int s_ = ei[i], d_ = ei[EE + i];
      pe[q] = ((uint)d_ << 16) | (uint)s_;
      int bb = d_ >> 8;
      be[q] = bb;
      re[q] = atomicAdd(&h[bb], 1);
    }
  }
  __syncthreads();
  int v = (t < NB) ? h[t] : 0;
  sc[t] = v;
  __syncthreads();
  for (int off = 1; off < 256; off <<= 1){
    int add = (t >= off) ? sc[t-off] : 0;
    __syncthreads();
    sc[t] += add;
    __syncthreads();
  }
  if (t < NB){
    int lofs = sc[t] - v;
    int g = v ? atomicAdd(&ecur[t], v) : 0;
    gdelta[t] = g - lofs;
    h[t] = lofs;
  }
  __syncthreads();
  #pragma unroll
  for (int q = 0; q < 8; ++q) if (be[q] >= 0){
    int j = h[be[q]] + re[q];
    P[j] = pe[q];
    A[j] = gdelta[be[q]] + j;
  }
  __syncthreads();
  for (int j = t; j < bc; j += 256) ebuf[A[j]] = P[j];
}

__global__ __launch_bounds__(256) void k_csr(const int* __restrict__ bcnt, const int* __restrict__ ebase,
                                             const uint* __restrict__ ebuf,
                                             int* __restrict__ rowptr, ushort* __restrict__ csr){
  __shared__ uint  sbuf[CAP];
  __shared__ ushort rnk[CAP];
  __shared__ int h[256];
  __shared__ int sc[256];
  int b = blockIdx.x, t = threadIdx.x;
  int nd0 = b * 256;
  int ncnt = NN - nd0; if (ncnt > 256) ncnt = 256;
  int cnt = bcnt[b]; if (cnt > CAP) cnt = CAP;
  int e0 = ebase[b];
  int cb = e0 + nd0;
  h[t] = (t < ncnt) ? 1 : 0;
  for (int j = t; j < cnt; j += 256) sbuf[j] = ebuf[e0 + j];
  __syncthreads();
  for (int j = t; j < cnt; j += 256){
    int local = (sbuf[j] >> 16) & 255;
    rnk[j] = (ushort)atomicAdd(&h[local], 1);
  }
  __syncthreads();
  int v = h[t];
  sc[t] = v;
  __syncthreads();
  for (int off = 1; off < 256; off <<= 1){
    int add = (t >= off) ? sc[t-off] : 0;
    __syncthreads();
    sc[t] += add;
    __syncthreads();
  }
  h[t] = sc[t] - v;
  __syncthreads();
  if (t < ncnt){
    int rp = cb + h[t];
    rowptr[nd0 + t] = rp;
    csr[rp] = (ushort)(nd0 + t);
  }
  if (b == NB-1 && t == 0) rowptr[NN] = TE;
  for (int j = t; j < cnt; j += 256){
    uint p = sbuf[j];
    int local = (p >> 16) & 255;
    csr[cb + h[local] + (int)rnk[j]] = (ushort)(p & 0xFFFFu);
  }
}

// ---------------- GEMM1: h1 = x @ W1 (+ fused attention dots), bf16 output ----------------
// 64 rows/block (grid 782), 256 thr: rg=tid>>4 (16), cg=tid&15 (16).
// Thread: rows rg+16*jr (jr 0..3), cols cg*4 + 64*jc (jc 0..1). Conflict-free LDS.
__global__ __launch_bounds__(256, 3) void k_gemm1(const float* __restrict__ x, const float* __restrict__ W,
    const float* __restrict__ a_src, const float* __restrict__ a_dst,
    uint* __restrict__ h1b, float* __restrict__ al_s, float* __restrict__ al_d){
  __shared__ float Ws[64*128];      // 32 KB (one K-half)
  __shared__ float xs[64*68];       // 17 KB, stride 68 (16B aligned, bank-spread)
  int tid = threadIdx.x;
  int row0 = blockIdx.x * 64;
  int rg = tid >> 4;                // 0..15
  int cg = tid & 15;                // 0..15
  float acc[32];                    // [jr][jc*4+q]
  #pragma unroll
  for (int i = 0; i < 32; ++i) acc[i] = 0.f;
  const float4* W4 = (const float4*)W;
  const float4* x4 = (const float4*)x;
  float4* Ws4 = (float4*)Ws;

  for (int kh = 0; kh < 2; ++kh){
    if (kh) __syncthreads();
    #pragma unroll
    for (int f0 = 0; f0 < 2048; f0 += 256){
      int f = f0 + tid;
      Ws4[f] = W4[kh*2048 + f];     // W half contiguous [64][128]
    }
    #pragma unroll
    for (int f0 = 0; f0 < 1024; f0 += 256){
      int f = f0 + tid;
      int row = f >> 4, kq = f & 15;
      float4 v = make_float4(0.f,0.f,0.f,0.f);
      if (row0 + row < NN) v = x4[(size_t)(row0+row)*32 + kh*16 + kq];
      *(float4*)(xs + row*68 + kq*4) = v;
    }
    __syncthreads();

    for (int k4 = 0; k4 < 16; ++k4){
      float4 xv0 = *(const float4*)(xs + (rg     )*68 + k4*4);
      float4 xv1 = *(const float4*)(xs + (rg + 16)*68 + k4*4);
      float4 xv2 = *(const float4*)(xs + (rg + 32)*68 + k4*4);
      float4 xv3 = *(const float4*)(xs + (rg + 48)*68 + k4*4);
      #pragma unroll
      for (int kk = 0; kk < 4; ++kk){
        const float4* wr = (const float4*)(Ws + (k4*4+kk)*128);
        float4 w0 = wr[cg], w1 = wr[cg+16];
        float xk0 = (&xv0.x)[kk], xk1 = (&xv1.x)[kk], xk2 = (&xv2.x)[kk], xk3 = (&xv3.x)[kk];
        #define FMA_ROW(jr, xk) \
          acc[jr*8+0] += xk*w0.x; acc[jr*8+1] += xk*w0.y; acc[jr*8+2] += xk*w0.z; acc[jr*8+3] += xk*w0.w; \
          acc[jr*8+4] += xk*w1.x; acc[jr*8+5] += xk*w1.y; acc[jr*8+6] += xk*w1.z; acc[jr*8+7] += xk*w1.w;
        FMA_ROW(0, xk0) FMA_ROW(1, xk1) FMA_ROW(2, xk2) FMA_ROW(3, xk3)
        #undef FMA_ROW
      }
    }
  }

  #pragma unroll
  for (int jr = 0; jr < 4; ++jr){
    int n = row0 + rg + 16*jr;
    bool ok = (n < NN);
    uint* orow = h1b + (size_t)n*64;
    #pragma unroll
    for (int jc = 0; jc < 2; ++jc){
      float4 v = make_float4(acc[jr*8+jc*4], acc[jr*8+jc*4+1], acc[jr*8+jc*4+2], acc[jr*8+jc*4+3]);
      if (ok){
        uint2 pv = make_uint2(pack_bf16(v.x, v.y), pack_bf16(v.z, v.w));
        *(uint2*)(orow + jc*32 + cg*2) = pv;    // cols jc*64 + cg*4 .. +3
      }
      int ab = jc*64 + cg*4;                    // within-head offset: heads are 32-wide
      float ps = v.x*a_src[ab] + v.y*a_src[ab+1] + v.z*a_src[ab+2] + v.w*a_src[ab+3];
      float pd = v.x*a_dst[ab] + v.y*a_dst[ab+1] + v.z*a_dst[ab+2] + v.w*a_dst[ab+3];
      // 8 cg's (cg&7) share a head; lanes differ in bits 0..2 of tid
      ps += __shfl_xor(ps, 1); ps += __shfl_xor(ps, 2); ps += __shfl_xor(ps, 4);
      pd += __shfl_xor(pd, 1); pd += __shfl_xor(pd, 2); pd += __shfl_xor(pd, 4);
      if (ok && (cg & 7) == 0){
        int h = (cg >> 3) + 2*jc;               // cg=0 -> heads 0/2, cg=8 -> heads 1/3
        al_s[n*4 + h] = ps; al_d[n*4 + h] = pd;
      }
    }
  }
}

// ---------------- layer-1 aggregation: half-wave per edge, uint2 loads, bf16 out ----------------
__global__ __launch_bounds__(256) void k_agg1(const int* __restrict__ rowptr, const ushort* __restrict__ csr,
    const uint* __restrict__ h1b, const float* __restrict__ al_s, const float* __restrict__ al_d,
    const float* __restrict__ b1, uint* __restrict__ h2b){
  int wid  = (blockIdx.x*256 + threadIdx.x) >> 6;   // node id (1 wave per node)
  int lane = threadIdx.x & 63;
  if (wid >= NN) return;
  int half = lane >> 5;               // 0: even edges, 1: odd edges
  int li   = lane & 31;               // lane owns channels 4li..4li+3
  int h    = li >> 3;                 // head of those channels
  float ad = al_d[wid*4 + h];
  int rs = rowptr[wid], re = rowptr[wid+1];
  float a0 = 0.f, a1 = 0.f, a2 = 0.f, a3 = 0.f, den = 0.f;
  int i = rs + half;
  for (; i + 2 < re; i += 4){         // two edges per lane per iter
    int s0 = csr[i], s1 = csr[i+2];
    float e0 = al_s[s0*4 + h], e1 = al_s[s1*4 + h];
    uint2 u0 = *(const uint2*)(h1b + (size_t)s0*64 + li*2);
    uint2 u1 = *(const uint2*)(h1b + (size_t)s1*64 + li*2);
    float ex0 = __expf(lrelu(e0 + ad));
    float ex1 = __expf(lrelu(e1 + ad));
    den += ex0 + ex1;
    a0 += ex0*bf_lo(u0.x) + ex1*bf_lo(u1.x);
    a1 += ex0*bf_hi(u0.x) + ex1*bf_hi(u1.x);
    a2 += ex0*bf_lo(u0.y) + ex1*bf_lo(u1.y);
    a3 += ex0*bf_hi(u0.y) + ex1*bf_hi(u1.y);
  }
  for (; i < re; i += 2){
    int s0 = csr[i];
    float ex = __expf(lrelu(al_s[s0*4 + h] + ad));
    uint2 u = *(const uint2*)(h1b + (size_t)s0*64 + li*2);
    den += ex;
    a0 += ex*bf_lo(u.x); a1 += ex*bf_hi(u.x);
    a2 += ex*bf_lo(u.y); a3 += ex*bf_hi(u.y);
  }
  den += __shfl_xor(den, 32);
  a0  += __shfl_xor(a0, 32);
  a1  += __shfl_xor(a1, 32);
  a2  += __shfl_xor(a2, 32);
  a3  += __shfl_xor(a3, 32);
  if (half == 0){
    float inv = 1.f/(den + 1e-16f);
    float4 bb = *(const float4*)(b1 + li*4);
    float o0 = a0*inv + bb.x, o1 = a1*inv + bb.y, o2 = a2*inv + bb.z, o3 = a3*inv + bb.w;
    o0 = o0 > 0.f ? o0 : (__expf(o0) - 1.f);        // ELU fused
    o1 = o1 > 0.f ? o1 : (__expf(o1) - 1.f);
    o2 = o2 > 0.f ? o2 : (__expf(o2) - 1.f);
    o3 = o3 > 0.f ? o3 : (__expf(o3) - 1.f);
    *(uint2*)(h2b + (size_t)wid*64 + li*2) = make_uint2(pack_bf16(o0,o1), pack_bf16(o2,o3));
  }
}

// ---------------- GEMM2: g = h2 @ W2 (+ fused attention dots), bf16 in/out ----------------
// 64 rows/block (grid 782), thread: 4 rows x 4 cols.
__global__ __launch_bounds__(256, 3) void k_gemm2(const uint* __restrict__ h2b, const float* __restrict__ W,
    const float* __restrict__ a_src, const float* __restrict__ a_dst,
    uint* __restrict__ gb, float* __restrict__ al_s, float* __restrict__ al_d){
  __shared__ float Ws[64*64];       // 16 KB (one K-half)
  __shared__ float xs[64*68];       // 17 KB
  int tid = threadIdx.x;
  int row0 = blockIdx.x * 64;
  int rg = tid >> 4;                // 0..15
  int cg = tid & 15;                // 0..15 -> cols cg*4..+3
  float acc[16];
  #pragma unroll
  for (int i = 0; i < 16; ++i) acc[i] = 0.f;
  const float4* W4 = (const float4*)W;
  const uint4* x4 = (const uint4*)h2b;
  float4* Ws4 = (float4*)Ws;

  for (int kh = 0; kh < 2; ++kh){
    if (kh) __syncthreads();
    #pragma unroll
    for (int f0 = 0; f0 < 1024; f0 += 256){
      int f = f0 + tid;
      Ws4[f] = W4[kh*1024 + f];     // W2 half contiguous [64][64]
    }
    #pragma unroll
    for (int f0 = 0; f0 < 512; f0 += 256){
      int f = f0 + tid;
      int row = f >> 3, q = f & 7;            // 8 uint4 per row-half (32 uints = 64 floats)
      uint4 u = make_uint4(0,0,0,0);
      if (row0 + row < NN) u = x4[(size_t)(row0+row)*16 + kh*8 + q];
      float* xp = xs + row*68 + q*8;
      *(float4*)xp     = make_float4(bf_lo(u.x), bf_hi(u.x), bf_lo(u.y), bf_hi(u.y));
      *(float4*)(xp+4) = make_float4(bf_lo(u.z), bf_hi(u.z), bf_lo(u.w), bf_hi(u.w));
    }
    __syncthreads();

    for (int k4 = 0; k4 < 16; ++k4){
      float4 xv0 = *(const float4*)(xs + (rg     )*68 + k4*4);
      float4 xv1 = *(const float4*)(xs + (rg + 16)*68 + k4*4);
      float4 xv2 = *(const float4*)(xs + (rg + 32)*68 + k4*4);
      float4 xv3 = *(const float4*)(xs + (rg + 48)*68 + k4*4);
      #pragma unroll
      for (int kk = 0; kk < 4; ++kk){
        float4 w0 = *(const float4*)(Ws + (k4*4+kk)*64 + cg*4);
        float xk0 = (&xv0.x)[kk], xk1 = (&xv1.x)[kk], xk2 = (&xv2.x)[kk], xk3 = (&xv3.x)[kk];
        #define FMA_ROW2(jr, xk) \
          acc[jr*4+0] += xk*w0.x; acc[jr*4+1] += xk*w0.y; acc[jr*4+2] += xk*w0.z; acc[jr*4+3] += xk*w0.w;
        FMA_ROW2(0, xk0) FMA_ROW2(1, xk1) FMA_ROW2(2, xk2) FMA_ROW2(3, xk3)
        #undef FMA_ROW2
      }
    }
  }

  #pragma unroll
  for (int jr = 0; jr < 4; ++jr){
    int n = row0 + rg + 16*jr;
    bool ok = (n < NN);
    float4 v = make_float4(acc[jr*4+0], acc[jr*4+1], acc[jr*4+2], acc[jr*4+3]);
    if (ok){
      uint* orow = gb + (size_t)n*32;
      *(uint2*)(orow + cg*2) = make_uint2(pack_bf16(v.x, v.y), pack_bf16(v.z, v.w));
    }
    int ab = cg*4;
    float ps = v.x*a_src[ab] + v.y*a_src[ab+1] + v.z*a_src[ab+2] + v.w*a_src[ab+3];
    float pd = v.x*a_dst[ab] + v.y*a_dst[ab+1] + v.z*a_dst[ab+2] + v.w*a_dst[ab+3];
    ps += __shfl_xor(ps, 1); ps += __shfl_xor(ps, 2); ps += __shfl_xor(ps, 4); ps += __shfl_xor(ps, 8);
    pd += __shfl_xor(pd, 1); pd += __shfl_xor(pd, 2); pd += __shfl_xor(pd, 4); pd += __shfl_xor(pd, 8);
    if (ok && cg == 0){ al_s[n] = ps; al_d[n] = pd; }
  }
}

// ---------------- layer-2 aggregation: half-wave per edge, uint loads -> d_out ----------------
__global__ __launch_bounds__(256) void k_agg2(const int* __restrict__ rowptr, const ushort* __restrict__ csr,
    const uint* __restrict__ gb, const float* __restrict__ al_s, const float* __restrict__ al_d,
    const float* __restrict__ b2, float* __restrict__ out){
  int wid  = (blockIdx.x*256 + threadIdx.x) >> 6;   // node id (1 wave per node)
  int lane = threadIdx.x & 63;
  if (wid >= NN) return;
  int half = lane >> 5;
  int li   = lane & 31;               // lane owns channels 2li, 2li+1
  float ad = al_d[wid];
  int rs = rowptr[wid], re = rowptr[wid+1];
  float a0 = 0.f, a1 = 0.f, den = 0.f;
  int i = rs + half;
  for (; i + 2 < re; i += 4){
    int s0 = csr[i], s1 = csr[i+2];
    float e0 = al_s[s0], e1 = al_s[s1];
    uint u0 = gb[(size_t)s0*32 + li];
    uint u1 = gb[(size_t)s1*32 + li];
    float ex0 = __expf(lrelu(e0 + ad));
    float ex1 = __expf(lrelu(e1 + ad));
    den += ex0 + ex1;
    a0 += ex0*bf_lo(u0) + ex1*bf_lo(u1);
    a1 += ex0*bf_hi(u0) + ex1*bf_hi(u1);
  }
  for (; i < re; i += 2){
    int s0 = csr[i];
    float ex = __expf(lrelu(al_s[s0] + ad));
    uint u = gb[(size_t)s0*32 + li];
    den += ex;
    a0 += ex*bf_lo(u); a1 += ex*bf_hi(u);
  }
  den += __shfl_xor(den, 32);
  a0  += __shfl_xor(a0, 32);
  a1  += __shfl_xor(a1, 32);
  if (half == 0){
    float inv = 1.f/(den + 1e-16f);
    float2 bb = *(const float2*)(b2 + li*2);
    *(float2*)(out + (size_t)wid*64 + li*2) = make_float2(a0*inv + bb.x, a1*inv + bb.y);
  }
}

extern "C" void kernel_launch(void* const* d_in, const int* in_sizes, int n_in,
                              void* d_out, int out_size, void* d_ws, size_t ws_size,
                              hipStream_t stream){
  const float* x   = (const float*)d_in[0];
  const int*   ei  = (const int*)d_in[1];
  const float* W1  = (const float*)d_in[2];
  const float* as1 = (const float*)d_in[3];
  const float* ad1 = (const float*)d_in[4];
  const float* b1  = (const float*)d_in[5];
  const float* W2  = (const float*)d_in[6];
  const float* as2 = (const float*)d_in[7];
  const float* ad2 = (const float*)d_in[8];
  const float* b2  = (const float*)d_in[9];
  float* out = (float*)d_out;
  (void)in_sizes; (void)n_in; (void)out_size; (void)ws_size;

  char* p = (char*)d_ws;
  size_t off = 0;
  auto alloc = [&](size_t bytes)->char*{
    char* r = p + off; off += (bytes + 255) & ~size_t(255); return r;
  };
  uint*  h1b   = (uint*)alloc((size_t)NN*64*4);     // bf16-packed [N][128]
  uint*  h2b   = (uint*)alloc((size_t)NN*64*4);     // bf16-packed [N][128]
  uint*  gb    = (uint*)alloc((size_t)NN*32*4);     // bf16-packed [N][64]
  float* al1s  = (float*)alloc((size_t)NN*4*4);
  float* al1d  = (float*)alloc((size_t)NN*4*4);
  float* al2s  = (float*)alloc((size_t)NN*4);
  float* al2d  = (float*)alloc((size_t)NN*4);
  int*   rowptr= (int*)alloc((size_t)(NN+1)*4);
  ushort* csr  = (ushort*)alloc((size_t)TE*2);
  uint*  ebuf  = (uint*)alloc((size_t)EE*4);
  int*   bcnt  = (int*)alloc((size_t)NB*4);
  int*   ebase = (int*)alloc((size_t)NB*4);
  int*   ecur  = (int*)alloc((size_t)NB*4);

  k_zero<<<1, 256, 0, stream>>>(bcnt);
  k_bcount<<<NBLK, 256, 0, stream>>>(ei, bcnt);
  k_bscan2<<<1, 256, 0, stream>>>(bcnt, ebase, ecur);
  k_bucketize<<<NBLK, 256, 0, stream>>>(ei, ecur, ebuf);
  k_csr<<<NB, 256, 0, stream>>>(bcnt, ebase, ebuf, rowptr, csr);
  k_gemm1<<<(NN+63)/64, 256, 0, stream>>>(x, W1, as1, ad1, h1b, al1s, al1d);
  k_agg1<<<(NN*64+255)/256, 256, 0, stream>>>(rowptr, csr, h1b, al1s, al1d, b1, h2b);
  k_gemm2<<<(NN+63)/64, 256, 0, stream>>>(h2b, W2, as2, ad2, gb, al2s, al2d);
  k_agg2<<<(NN*64+255)/256, 256, 0, stream>>>(rowptr, csr, gb, al2s, al2d, b2, out);
}

// Round 7
// 163.690 us; speedup vs baseline: 1.0720x; 1.0720x over previous
//
#include <hip/hip_runtime.h>

#define NN 50000
#define EE 800000
#define TE (EE + NN)     // total edges including self loops
#define NB 196           // dst buckets of 256 nodes
#define CHUNK 2048       // edges per bucketize block
#define NBLK ((EE + CHUNK - 1) / CHUNK)   // 391
#define CAP 6144         // max edges per bucket

typedef unsigned int uint;
typedef unsigned short ushort;
typedef __attribute__((ext_vector_type(8))) short bf16x8;
typedef __attribute__((ext_vector_type(4))) float f32x4;

__device__ __forceinline__ float lrelu(float v){ return v > 0.f ? v : 0.2f*v; }
// round-to-nearest-even fp32 -> bf16
__device__ __forceinline__ ushort bf16r(float a){
  uint ua = __float_as_uint(a);
  return (ushort)((ua + 0x7FFFu + ((ua >> 16) & 1u)) >> 16);
}
__device__ __forceinline__ uint pack_bf16(float a, float b){
  return (uint)bf16r(a) | ((uint)bf16r(b) << 16);
}
__device__ __forceinline__ float bf_lo(uint u){ return __uint_as_float(u << 16); }
__device__ __forceinline__ float bf_hi(uint u){ return __uint_as_float(u & 0xFFFF0000u); }

// ---------------- CSR build (bucketed, no per-edge global atomics) ----------------
__global__ __launch_bounds__(256) void k_zero(int* __restrict__ bcnt){
  int t = threadIdx.x;
  if (t < NB) bcnt[t] = 0;
}

__global__ __launch_bounds__(256) void k_bcount(const int* __restrict__ ei, int* __restrict__ bcnt){
  __shared__ int h[NB];
  int t = threadIdx.x;
  if (t < NB) h[t] = 0;
  __syncthreads();
  int base = blockIdx.x * CHUNK;
  int end = base + CHUNK; if (end > EE) end = EE;
  for (int i = base + t; i < end; i += 256)
    atomicAdd(&h[ei[EE + i] >> 8], 1);
  __syncthreads();
  if (t < NB && h[t]) atomicAdd(&bcnt[t], h[t]);
}

__global__ __launch_bounds__(256) void k_bscan2(const int* __restrict__ bcnt,
                                                int* __restrict__ ebase, int* __restrict__ ecur){
  __shared__ int s[256];
  int t = threadIdx.x;
  int v = (t < NB) ? bcnt[t] : 0;
  s[t] = v;
  __syncthreads();
  for (int off = 1; off < 256; off <<= 1){
    int add = (t >= off) ? s[t-off] : 0;
    __syncthreads();
    s[t] += add;
    __syncthreads();
  }
  if (t < NB){ int ex = s[t] - v; ebase[t] = ex; ecur[t] = ex; }
}

__global__ __launch_bounds__(256) void k_bucketize(const int* __restrict__ ei,
                                                   int* __restrict__ ecur, uint* __restrict__ ebuf){
  __shared__ int h[NB];
  __shared__ int sc[256];
  __shared__ int gdelta[NB];
  __shared__ uint P[CHUNK];
  __shared__ int  A[CHUNK];
  int t = threadIdx.x;
  if (t < NB) h[t] = 0;
  __syncthreads();
  int base = blockIdx.x * CHUNK;
  int end = base + CHUNK; if (end > EE) end = EE;
  int bc = end - base;
  int be[8]; int re[8]; uint pe[8];
  #pragma unroll
  for (int q = 0; q < 8; ++q){
    int i = base + t + q*256;
    be[q] = -1;
    if (i < end){
      int s_ = ei[i], d_ = ei[EE + i];
      pe[q] = ((uint)d_ << 16) | (uint)s_;
      int bb = d_ >> 8;
      be[q] = bb;
      re[q] = atomicAdd(&h[bb], 1);
    }
  }
  __syncthreads();
  int v = (t < NB) ? h[t] : 0;
  sc[t] = v;
  __syncthreads();
  for (int off = 1; off < 256; off <<= 1){
    int add = (t >= off) ? sc[t-off] : 0;
    __syncthreads();
    sc[t] += add;
    __syncthreads();
  }
  if (t < NB){
    int lofs = sc[t] - v;
    int g = v ? atomicAdd(&ecur[t], v) : 0;
    gdelta[t] = g - lofs;
    h[t] = lofs;
  }
  __syncthreads();
  #pragma unroll
  for (int q = 0; q < 8; ++q) if (be[q] >= 0){
    int j = h[be[q]] + re[q];
    P[j] = pe[q];
    A[j] = gdelta[be[q]] + j;
  }
  __syncthreads();
  for (int j = t; j < bc; j += 256) ebuf[A[j]] = P[j];
}

__global__ __launch_bounds__(256) void k_csr(const int* __restrict__ bcnt, const int* __restrict__ ebase,
                                             const uint* __restrict__ ebuf,
                                             int* __restrict__ rowptr, ushort* __restrict__ csr){
  __shared__ uint  sbuf[CAP];
  __shared__ ushort rnk[CAP];
  __shared__ int h[256];
  __shared__ int sc[256];
  int b = blockIdx.x, t = threadIdx.x;
  int nd0 = b * 256;
  int ncnt = NN - nd0; if (ncnt > 256) ncnt = 256;
  int cnt = bcnt[b]; if (cnt > CAP) cnt = CAP;
  int e0 = ebase[b];
  int cb = e0 + nd0;
  h[t] = (t < ncnt) ? 1 : 0;
  for (int j = t; j < cnt; j += 256) sbuf[j] = ebuf[e0 + j];
  __syncthreads();
  for (int j = t; j < cnt; j += 256){
    int local = (sbuf[j] >> 16) & 255;
    rnk[j] = (ushort)atomicAdd(&h[local], 1);
  }
  __syncthreads();
  int v = h[t];
  sc[t] = v;
  __syncthreads();
  for (int off = 1; off < 256; off <<= 1){
    int add = (t >= off) ? sc[t-off] : 0;
    __syncthreads();
    sc[t] += add;
    __syncthreads();
  }
  h[t] = sc[t] - v;
  __syncthreads();
  if (t < ncnt){
    int rp = cb + h[t];
    rowptr[nd0 + t] = rp;
    csr[rp] = (ushort)(nd0 + t);
  }
  if (b == NB-1 && t == 0) rowptr[NN] = TE;
  for (int j = t; j < cnt; j += 256){
    uint p = sbuf[j];
    int local = (p >> 16) & 255;
    csr[cb + h[local] + (int)rnk[j]] = (ushort)(p & 0xFFFFu);
  }
}

// ---------------- GEMM1 (MFMA): h1 = x @ W1 (+ fused attention dots), bf16 out ----------------
// 64 rows/block, 4 waves x 16 rows, N=128 (8 col-tiles), K=128 (4 k-steps of 32).
// A staged [m][136] bf16, W^T staged [n][136] bf16 -> symmetric b128 frag reads (layout-robust).
__global__ __launch_bounds__(256, 3) void k_gemm1(const float* __restrict__ x, const float* __restrict__ W,
    const float* __restrict__ a_src, const float* __restrict__ a_dst,
    uint* __restrict__ h1b, float* __restrict__ al_s, float* __restrict__ al_d){
  __shared__ ushort Wt[128*136];   // [n][k] ~34 KB
  __shared__ ushort Ash[64*136];   // [m][k] ~17 KB
  int tid = threadIdx.x;
  int row0 = blockIdx.x * 64;
  const float4* W4 = (const float4*)W;
  #pragma unroll
  for (int f0 = 0; f0 < 4096; f0 += 256){
    int idx4 = f0 + tid;
    int k = idx4 >> 5;              // W row (input dim)
    int n0 = (idx4 & 31) * 4;       // output cols
    float4 v = W4[idx4];
    Wt[(n0  )*136 + k] = bf16r(v.x);
    Wt[(n0+1)*136 + k] = bf16r(v.y);
    Wt[(n0+2)*136 + k] = bf16r(v.z);
    Wt[(n0+3)*136 + k] = bf16r(v.w);
  }
  const float4* x4 = (const float4*)x;
  #pragma unroll
  for (int f0 = 0; f0 < 2048; f0 += 256){
    int idx4 = f0 + tid;
    int row = idx4 >> 5;
    int q = idx4 & 31;
    float4 v = make_float4(0.f,0.f,0.f,0.f);
    if (row0 + row < NN) v = x4[(size_t)(row0+row)*32 + q];
    *(uint2*)(Ash + row*136 + q*4) = make_uint2(pack_bf16(v.x, v.y), pack_bf16(v.z, v.w));
  }
  __syncthreads();

  int w = tid >> 6, lane = tid & 63;
  int lm = lane & 15, lg = lane >> 4;
  const ushort* Ab = Ash + (w*16 + lm)*136 + lg*8;
  const ushort* Bb = Wt + lm*136 + lg*8;
  f32x4 acc[8];
  #pragma unroll
  for (int i = 0; i < 8; ++i) acc[i] = (f32x4){0.f,0.f,0.f,0.f};
  #pragma unroll
  for (int ks = 0; ks < 4; ++ks){
    bf16x8 af = *(const bf16x8*)(Ab + ks*32);
    #pragma unroll
    for (int ct = 0; ct < 8; ++ct){
      bf16x8 bfr = *(const bf16x8*)(Bb + ct*16*136 + ks*32);
      acc[ct] = __builtin_amdgcn_mfma_f32_16x16x32_bf16(af, bfr, acc[ct], 0, 0, 0);
    }
  }
  // epilogue: acc[ct][r] -> (row = lg*4+r, col = ct*16+lm)
  int nbase = row0 + w*16 + lg*4;
  float ps[4][4], pd[4][4];
  #pragma unroll
  for (int h = 0; h < 4; ++h)
    #pragma unroll
    for (int r = 0; r < 4; ++r){ ps[h][r] = 0.f; pd[h][r] = 0.f; }
  #pragma unroll
  for (int ct = 0; ct < 8; ++ct){
    int col = ct*16 + lm;
    float ac = a_src[col], dc = a_dst[col];
    #pragma unroll
    for (int r = 0; r < 4; ++r){
      float v = acc[ct][r];
      ps[ct>>1][r] += v*ac;
      pd[ct>>1][r] += v*dc;
      float vp = __shfl_xor(v, 1);
      if ((lm & 1) == 0 && nbase + r < NN)
        h1b[(size_t)(nbase+r)*64 + ct*8 + (lm>>1)] = pack_bf16(v, vp);
    }
  }
  #pragma unroll
  for (int h = 0; h < 4; ++h)
    #pragma unroll
    for (int r = 0; r < 4; ++r){
      float s = ps[h][r], d = pd[h][r];
      s += __shfl_xor(s,1); s += __shfl_xor(s,2); s += __shfl_xor(s,4); s += __shfl_xor(s,8);
      d += __shfl_xor(d,1); d += __shfl_xor(d,2); d += __shfl_xor(d,4); d += __shfl_xor(d,8);
      if (lm == 0 && nbase + r < NN){
        al_s[(nbase+r)*4 + h] = s;
        al_d[(nbase+r)*4 + h] = d;
      }
    }
}

// ---------------- layer-1 aggregation: half-wave per edge, uint2 loads, bf16 out ----------------
__global__ __launch_bounds__(256) void k_agg1(const int* __restrict__ rowptr, const ushort* __restrict__ csr,
    const uint* __restrict__ h1b, const float* __restrict__ al_s, const float* __restrict__ al_d,
    const float* __restrict__ b1, uint* __restrict__ h2b){
  int wid  = (blockIdx.x*256 + threadIdx.x) >> 6;   // node id (1 wave per node)
  int lane = threadIdx.x & 63;
  if (wid >= NN) return;
  int half = lane >> 5;
  int li   = lane & 31;               // lane owns channels 4li..4li+3
  int h    = li >> 3;
  float ad = al_d[wid*4 + h];
  int rs = rowptr[wid], re = rowptr[wid+1];
  float a0 = 0.f, a1 = 0.f, a2 = 0.f, a3 = 0.f, den = 0.f;
  int i = rs + half;
  for (; i + 2 < re; i += 4){
    int s0 = csr[i], s1 = csr[i+2];
    float e0 = al_s[s0*4 + h], e1 = al_s[s1*4 + h];
    uint2 u0 = *(const uint2*)(h1b + (size_t)s0*64 + li*2);
    uint2 u1 = *(const uint2*)(h1b + (size_t)s1*64 + li*2);
    float ex0 = __expf(lrelu(e0 + ad));
    float ex1 = __expf(lrelu(e1 + ad));
    den += ex0 + ex1;
    a0 += ex0*bf_lo(u0.x) + ex1*bf_lo(u1.x);
    a1 += ex0*bf_hi(u0.x) + ex1*bf_hi(u1.x);
    a2 += ex0*bf_lo(u0.y) + ex1*bf_lo(u1.y);
    a3 += ex0*bf_hi(u0.y) + ex1*bf_hi(u1.y);
  }
  for (; i < re; i += 2){
    int s0 = csr[i];
    float ex = __expf(lrelu(al_s[s0*4 + h] + ad));
    uint2 u = *(const uint2*)(h1b + (size_t)s0*64 + li*2);
    den += ex;
    a0 += ex*bf_lo(u.x); a1 += ex*bf_hi(u.x);
    a2 += ex*bf_lo(u.y); a3 += ex*bf_hi(u.y);
  }
  den += __shfl_xor(den, 32);
  a0  += __shfl_xor(a0, 32);
  a1  += __shfl_xor(a1, 32);
  a2  += __shfl_xor(a2, 32);
  a3  += __shfl_xor(a3, 32);
  if (half == 0){
    float inv = 1.f/(den + 1e-16f);
    float4 bb = *(const float4*)(b1 + li*4);
    float o0 = a0*inv + bb.x, o1 = a1*inv + bb.y, o2 = a2*inv + bb.z, o3 = a3*inv + bb.w;
    o0 = o0 > 0.f ? o0 : (__expf(o0) - 1.f);        // ELU fused
    o1 = o1 > 0.f ? o1 : (__expf(o1) - 1.f);
    o2 = o2 > 0.f ? o2 : (__expf(o2) - 1.f);
    o3 = o3 > 0.f ? o3 : (__expf(o3) - 1.f);
    *(uint2*)(h2b + (size_t)wid*64 + li*2) = make_uint2(pack_bf16(o0,o1), pack_bf16(o2,o3));
  }
}

// ---------------- GEMM2 (MFMA): g = h2 @ W2 (+ fused attention dots), bf16 in/out ----------------
// 64 rows/block, N=64 (4 col-tiles), K=128.
__global__ __launch_bounds__(256, 4) void k_gemm2(const uint* __restrict__ h2b, const float* __restrict__ W,
    const float* __restrict__ a_src, const float* __restrict__ a_dst,
    uint* __restrict__ gb, float* __restrict__ al_s, float* __restrict__ al_d){
  __shared__ ushort Wt[64*136];    // [n][k] ~17 KB
  __shared__ ushort Ash[64*136];   // [m][k] ~17 KB
  int tid = threadIdx.x;
  int row0 = blockIdx.x * 64;
  const float4* W4 = (const float4*)W;
  #pragma unroll
  for (int f0 = 0; f0 < 2048; f0 += 256){
    int idx4 = f0 + tid;
    int k = idx4 >> 4;              // W2 row (input dim, 16 float4 per row)
    int n0 = (idx4 & 15) * 4;
    float4 v = W4[idx4];
    Wt[(n0  )*136 + k] = bf16r(v.x);
    Wt[(n0+1)*136 + k] = bf16r(v.y);
    Wt[(n0+2)*136 + k] = bf16r(v.z);
    Wt[(n0+3)*136 + k] = bf16r(v.w);
  }
  #pragma unroll
  for (int f0 = 0; f0 < 4096; f0 += 256){
    int idx = f0 + tid;
    int row = idx >> 6;
    int q = idx & 63;               // uint (2 bf16) within row
    uint u = 0;
    if (row0 + row < NN) u = h2b[(size_t)(row0+row)*64 + q];
    *(uint*)(Ash + row*136 + q*2) = u;
  }
  __syncthreads();

  int w = tid >> 6, lane = tid & 63;
  int lm = lane & 15, lg = lane >> 4;
  const ushort* Ab = Ash + (w*16 + lm)*136 + lg*8;
  const ushort* Bb = Wt + lm*136 + lg*8;
  f32x4 acc[4];
  #pragma unroll
  for (int i = 0; i < 4; ++i) acc[i] = (f32x4){0.f,0.f,0.f,0.f};
  #pragma unroll
  for (int ks = 0; ks < 4; ++ks){
    bf16x8 af = *(const bf16x8*)(Ab + ks*32);
    #pragma unroll
    for (int ct = 0; ct < 4; ++ct){
      bf16x8 bfr = *(const bf16x8*)(Bb + ct*16*136 + ks*32);
      acc[ct] = __builtin_amdgcn_mfma_f32_16x16x32_bf16(af, bfr, acc[ct], 0, 0, 0);
    }
  }
  int nbase = row0 + w*16 + lg*4;
  float ps[4], pd[4];
  #pragma unroll
  for (int r = 0; r < 4; ++r){ ps[r] = 0.f; pd[r] = 0.f; }
  #pragma unroll
  for (int ct = 0; ct < 4; ++ct){
    int col = ct*16 + lm;
    float ac = a_src[col], dc = a_dst[col];
    #pragma unroll
    for (int r = 0; r < 4; ++r){
      float v = acc[ct][r];
      ps[r] += v*ac;
      pd[r] += v*dc;
      float vp = __shfl_xor(v, 1);
      if ((lm & 1) == 0 && nbase + r < NN)
        gb[(size_t)(nbase+r)*32 + ct*8 + (lm>>1)] = pack_bf16(v, vp);
    }
  }
  #pragma unroll
  for (int r = 0; r < 4; ++r){
    float s = ps[r], d = pd[r];
    s += __shfl_xor(s,1); s += __shfl_xor(s,2); s += __shfl_xor(s,4); s += __shfl_xor(s,8);
    d += __shfl_xor(d,1); d += __shfl_xor(d,2); d += __shfl_xor(d,4); d += __shfl_xor(d,8);
    if (lm == 0 && nbase + r < NN){
      al_s[nbase+r] = s;
      al_d[nbase+r] = d;
    }
  }
}

// ---------------- layer-2 aggregation: half-wave per edge, uint loads -> d_out ----------------
__global__ __launch_bounds__(256) void k_agg2(const int* __restrict__ rowptr, const ushort* __restrict__ csr,
    const uint* __restrict__ gb, const float* __restrict__ al_s, const float* __restrict__ al_d,
    const float* __restrict__ b2, float* __restrict__ out){
  int wid  = (blockIdx.x*256 + threadIdx.x) >> 6;   // node id (1 wave per node)
  int lane = threadIdx.x & 63;
  if (wid >= NN) return;
  int half = lane >> 5;
  int li   = lane & 31;               // lane owns channels 2li, 2li+1
  float ad = al_d[wid];
  int rs = rowptr[wid], re = rowptr[wid+1];
  float a0 = 0.f, a1 = 0.f, den = 0.f;
  int i = rs + half;
  for (; i + 2 < re; i += 4){
    int s0 = csr[i], s1 = csr[i+2];
    float e0 = al_s[s0], e1 = al_s[s1];
    uint u0 = gb[(size_t)s0*32 + li];
    uint u1 = gb[(size_t)s1*32 + li];
    float ex0 = __expf(lrelu(e0 + ad));
    float ex1 = __expf(lrelu(e1 + ad));
    den += ex0 + ex1;
    a0 += ex0*bf_lo(u0) + ex1*bf_lo(u1);
    a1 += ex0*bf_hi(u0) + ex1*bf_hi(u1);
  }
  for (; i < re; i += 2){
    int s0 = csr[i];
    float ex = __expf(lrelu(al_s[s0] + ad));
    uint u = gb[(size_t)s0*32 + li];
    den += ex;
    a0 += ex*bf_lo(u); a1 += ex*bf_hi(u);
  }
  den += __shfl_xor(den, 32);
  a0  += __shfl_xor(a0, 32);
  a1  += __shfl_xor(a1, 32);
  if (half == 0){
    float inv = 1.f/(den + 1e-16f);
    float2 bb = *(const float2*)(b2 + li*2);
    *(float2*)(out + (size_t)wid*64 + li*2) = make_float2(a0*inv + bb.x, a1*inv + bb.y);
  }
}

extern "C" void kernel_launch(void* const* d_in, const int* in_sizes, int n_in,
                              void* d_out, int out_size, void* d_ws, size_t ws_size,
                              hipStream_t stream){
  const float* x   = (const float*)d_in[0];
  const int*   ei  = (const int*)d_in[1];
  const float* W1  = (const float*)d_in[2];
  const float* as1 = (const float*)d_in[3];
  const float* ad1 = (const float*)d_in[4];
  const float* b1  = (const float*)d_in[5];
  const float* W2  = (const float*)d_in[6];
  const float* as2 = (const float*)d_in[7];
  const float* ad2 = (const float*)d_in[8];
  const float* b2  = (const float*)d_in[9];
  float* out = (float*)d_out;
  (void)in_sizes; (void)n_in; (void)out_size; (void)ws_size;

  char* p = (char*)d_ws;
  size_t off = 0;
  auto alloc = [&](size_t bytes)->char*{
    char* r = p + off; off += (bytes + 255) & ~size_t(255); return r;
  };
  uint*  h1b   = (uint*)alloc((size_t)NN*64*4);     // bf16-packed [N][128]
  uint*  h2b   = (uint*)alloc((size_t)NN*64*4);     // bf16-packed [N][128]
  uint*  gb    = (uint*)alloc((size_t)NN*32*4);     // bf16-packed [N][64]
  float* al1s  = (float*)alloc((size_t)NN*4*4);
  float* al1d  = (float*)alloc((size_t)NN*4*4);
  float* al2s  = (float*)alloc((size_t)NN*4);
  float* al2d  = (float*)alloc((size_t)NN*4);
  int*   rowptr= (int*)alloc((size_t)(NN+1)*4);
  ushort* csr  = (ushort*)alloc((size_t)TE*2);
  uint*  ebuf  = (uint*)alloc((size_t)EE*4);
  int*   bcnt  = (int*)alloc((size_t)NB*4);
  int*   ebase = (int*)alloc((size_t)NB*4);
  int*   ecur  = (int*)alloc((size_t)NB*4);

  k_zero<<<1, 256, 0, stream>>>(bcnt);
  k_bcount<<<NBLK, 256, 0, stream>>>(ei, bcnt);
  k_bscan2<<<1, 256, 0, stream>>>(bcnt, ebase, ecur);
  k_bucketize<<<NBLK, 256, 0, stream>>>(ei, ecur, ebuf);
  k_csr<<<NB, 256, 0, stream>>>(bcnt, ebase, ebuf, rowptr, csr);
  k_gemm1<<<(NN+63)/64, 256, 0, stream>>>(x, W1, as1, ad1, h1b, al1s, al1d);
  k_agg1<<<(NN*64+255)/256, 256, 0, stream>>>(rowptr, csr, h1b, al1s, al1d, b1, h2b);
  k_gemm2<<<(NN+63)/64, 256, 0, stream>>>(h2b, W2, as2, ad2, gb, al2s, al2d);
  k_agg2<<<(NN*64+255)/256, 256, 0, stream>>>(rowptr, csr, gb, al2s, al2d, b2, out);
}